// Round 1
// baseline (420.087 us; speedup 1.0000x reference)
//
#include <hip/hip_runtime.h>

#define BB  65536
#define INW 128
#define HH  256
#define MM  32
#define KK  (INW + HH)   // 384

typedef __attribute__((ext_vector_type(8))) short bf16x8;
typedef __attribute__((ext_vector_type(4))) float f32x4;

__device__ __forceinline__ unsigned f32_to_bf16(float f) {
    union { float f; unsigned u; } v; v.f = f;
    // round-to-nearest-even
    return (v.u + 0x7fffu + ((v.u >> 16) & 1u)) >> 16;
}

__device__ __forceinline__ bf16x8 cvt8(float4 a, float4 b) {
    bf16x8 r;
    r[0] = (short)f32_to_bf16(a.x); r[1] = (short)f32_to_bf16(a.y);
    r[2] = (short)f32_to_bf16(a.z); r[3] = (short)f32_to_bf16(a.w);
    r[4] = (short)f32_to_bf16(b.x); r[5] = (short)f32_to_bf16(b.y);
    r[6] = (short)f32_to_bf16(b.z); r[7] = (short)f32_to_bf16(b.w);
    return r;
}

__device__ __forceinline__ float rcp_f(float x) { return __builtin_amdgcn_rcpf(x); }
// sigmoid(x) = 1/(1+e^-x); saturates correctly at +/-inf via rcp(inf)=0
__device__ __forceinline__ float sigmoid_f(float x) { return rcp_f(1.0f + __expf(-x)); }
// tanh(x) = 1 - 2/(e^{2x}+1); exp overflow -> rcp(inf)=0 -> 1; exp->0 -> -1
__device__ __forceinline__ float tanh_f(float x) { return 1.0f - 2.0f * rcp_f(__expf(2.0f * x) + 1.0f); }

// ---- weight fp32 -> bf16 pre-conversion (run every call; d_ws is re-poisoned) ----
__global__ void cvt_weights(const float* __restrict__ Wi, const float* __restrict__ Wm,
                            unsigned short* __restrict__ Wi_bf, unsigned short* __restrict__ Wm_bf) {
    int i = blockIdx.x * 256 + threadIdx.x;
    if (i < HH * KK) Wi_bf[i] = (unsigned short)f32_to_bf16(Wi[i]);
    if (i < HH * MM) Wm_bf[i] = (unsigned short)f32_to_bf16(Wm[i]);
}

// ---- fused RLSTM: per-wave 16 rows x 128 cols, MFMA 16x16x32 bf16, no LDS ----
__global__ __launch_bounds__(256) void rlstm_main(
    const float* __restrict__ input, const float* __restrict__ media,
    const float* __restrict__ h_t,   const float* __restrict__ c_t,
    const unsigned short* __restrict__ Wi_bf, const float* __restrict__ bi,
    const unsigned short* __restrict__ Wm_bf, const float* __restrict__ bm,
    float* __restrict__ out)
{
    const int tid  = threadIdx.x;
    const int wave = tid >> 6;
    const int lane = tid & 63;
    const int lrow = lane & 15;   // A-row index within tile / C-col index
    const int quad = lane >> 4;   // k-group for A/B frags; row-group for C

    const int m0 = blockIdx.x * 32 + (wave >> 1) * 16;  // 16 batch rows per wave
    const int n0 = (wave & 1) * 128;                    // 8 col-tiles of 16

    f32x4 accg[8], accm[8];
#pragma unroll
    for (int t = 0; t < 8; ++t) {
        accg[t] = (f32x4){0.f, 0.f, 0.f, 0.f};
        accm[t] = (f32x4){0.f, 0.f, 0.f, 0.f};
    }

    const int arow = m0 + lrow;

    // ---- media GEMM: K=32, single chunk ----
    {
        const float4* ap = (const float4*)(media + (size_t)arow * MM + quad * 8);
        float4 a0 = ap[0], a1 = ap[1];
        bf16x8 af = cvt8(a0, a1);
        const unsigned short* wb = Wm_bf + (size_t)(n0 + lrow) * MM + quad * 8;
#pragma unroll
        for (int t = 0; t < 8; ++t) {
            bf16x8 bf = *(const bf16x8*)(wb + t * 16 * MM);
            accm[t] = __builtin_amdgcn_mfma_f32_16x16x32_bf16(af, bf, accm[t], 0, 0, 0);
        }
    }

    // ---- main GEMM part 1: k in [0,128) from input ----
    {
        const unsigned short* wbase = Wi_bf + (size_t)(n0 + lrow) * KK + quad * 8;
#pragma unroll
        for (int kc = 0; kc < 4; ++kc) {
            const float* src = input + (size_t)arow * INW + kc * 32 + quad * 8;
            float4 a0 = ((const float4*)src)[0];
            float4 a1 = ((const float4*)src)[1];
            bf16x8 af = cvt8(a0, a1);
            const unsigned short* wb = wbase + kc * 32;
#pragma unroll
            for (int t = 0; t < 8; ++t) {
                bf16x8 bf = *(const bf16x8*)(wb + t * 16 * KK);
                accg[t] = __builtin_amdgcn_mfma_f32_16x16x32_bf16(af, bf, accg[t], 0, 0, 0);
            }
        }
        // ---- main GEMM part 2: k in [128,384) from h_t ----
#pragma unroll
        for (int kc = 4; kc < 12; ++kc) {
            const float* src = h_t + (size_t)arow * HH + (kc - 4) * 32 + quad * 8;
            float4 a0 = ((const float4*)src)[0];
            float4 a1 = ((const float4*)src)[1];
            bf16x8 af = cvt8(a0, a1);
            const unsigned short* wb = wbase + kc * 32;
#pragma unroll
            for (int t = 0; t < 8; ++t) {
                bf16x8 bf = *(const bf16x8*)(wb + t * 16 * KK);
                accg[t] = __builtin_amdgcn_mfma_f32_16x16x32_bf16(af, bf, accg[t], 0, 0, 0);
            }
        }
    }

    // ---- epilogue: C/D layout col = n0+t*16+(lane&15), row = m0+quad*4+r ----
    const size_t outH = (size_t)BB * HH;
#pragma unroll
    for (int t = 0; t < 8; ++t) {
        const int col = n0 + t * 16 + lrow;
        const float bi_v = bi[col];
        const float bm_v = bm[col];
#pragma unroll
        for (int r = 0; r < 4; ++r) {
            const int row = m0 + quad * 4 + r;
            const size_t idx = (size_t)row * HH + col;
            float g    = accg[t][r] + bi_v;
            float mp   = accm[t][r] + bm_v;
            float gate = sigmoid_f(g);
            float tg   = tanh_f(g);
            float ct   = c_t[idx];
            float c    = ct * gate + tg * gate;
            float cr   = tanh_f(c);
            float mg   = sigmoid_f(mp);
            float cf   = c - cr + cr * mg;
            float h    = tanh_f(cf) * gate;
            out[idx]            = h;
            out[idx + outH]     = h;
            out[idx + 2 * outH] = c;
        }
    }
}

extern "C" void kernel_launch(void* const* d_in, const int* in_sizes, int n_in,
                              void* d_out, int out_size, void* d_ws, size_t ws_size,
                              hipStream_t stream) {
    const float* input = (const float*)d_in[0];
    const float* media = (const float*)d_in[1];
    const float* h_t   = (const float*)d_in[2];
    const float* c_t   = (const float*)d_in[3];
    const float* Wi    = (const float*)d_in[4];
    const float* bi    = (const float*)d_in[5];
    const float* Wm    = (const float*)d_in[6];
    const float* bm    = (const float*)d_in[7];
    float* out = (float*)d_out;

    unsigned short* Wi_bf = (unsigned short*)d_ws;
    unsigned short* Wm_bf = Wi_bf + HH * KK;

    hipLaunchKernelGGL(cvt_weights, dim3((HH * KK + 255) / 256), dim3(256), 0, stream,
                       Wi, Wm, Wi_bf, Wm_bf);
    hipLaunchKernelGGL(rlstm_main, dim3(BB / 32), dim3(256), 0, stream,
                       input, media, h_t, c_t, Wi_bf, bi, Wm_bf, bm, out);
}

// Round 2
// 391.681 us; speedup vs baseline: 1.0725x; 1.0725x over previous
//
#include <hip/hip_runtime.h>

#define BB  65536
#define INW 128
#define HH  256
#define MM  32
#define KK  (INW + HH)   // 384
#define NKC 12           // 32-wide K chunks in the main GEMM

typedef __attribute__((ext_vector_type(8))) short bf16x8;
typedef __attribute__((ext_vector_type(4))) float f32x4;

__device__ __forceinline__ unsigned short f32_to_bf16(float f) {
    union { float f; unsigned u; } v; v.f = f;
    return (unsigned short)((v.u + 0x7fffu + ((v.u >> 16) & 1u)) >> 16);
}

__device__ __forceinline__ bf16x8 cvt8(f32x4 a, f32x4 b) {
    bf16x8 r;
    r[0] = (short)f32_to_bf16(a[0]); r[1] = (short)f32_to_bf16(a[1]);
    r[2] = (short)f32_to_bf16(a[2]); r[3] = (short)f32_to_bf16(a[3]);
    r[4] = (short)f32_to_bf16(b[0]); r[5] = (short)f32_to_bf16(b[1]);
    r[6] = (short)f32_to_bf16(b[2]); r[7] = (short)f32_to_bf16(b[3]);
    return r;
}

__device__ __forceinline__ float rcp_f(float x) { return __builtin_amdgcn_rcpf(x); }
__device__ __forceinline__ float sigmoid_f(float x) { return rcp_f(1.0f + __expf(-x)); }
__device__ __forceinline__ float tanh_f(float x) { return 1.0f - 2.0f * rcp_f(__expf(2.0f * x) + 1.0f); }

// ---- weight fp32 -> bf16, packed fragment-major ----
// Wi packed layout: half h (n0 = h*128) | kc in [0,12) | t in [0,8) | lane*8+j
//   element = Wi[(h*128 + t*16 + (lane&15)) * KK + kc*32 + (lane>>4)*8 + j]
// Wm packed layout: half h | t in [0,8) | lane*8+j
//   element = Wm[(h*128 + t*16 + (lane&15)) * MM + (lane>>4)*8 + j]
__global__ void pack_weights(const float* __restrict__ Wi, const float* __restrict__ Wm,
                             unsigned short* __restrict__ Wi_p, unsigned short* __restrict__ Wm_p) {
    int id = blockIdx.x * 256 + threadIdx.x;     // packed element index
    if (id < 2 * NKC * 8 * 512) {
        int blk = id >> 9;          // 1KB fragment block
        int e   = id & 511;
        int lane = e >> 3, j = e & 7;
        int lrow = lane & 15, quad = lane >> 4;
        int h  = blk / (NKC * 8);
        int b  = blk % (NKC * 8);
        int kc = b >> 3;
        int t  = b & 7;
        int n  = h * 128 + t * 16 + lrow;
        int k  = kc * 32 + quad * 8 + j;
        Wi_p[id] = f32_to_bf16(Wi[(size_t)n * KK + k]);
    }
    if (id < 2 * 8 * 512) {
        int blk = id >> 9;
        int e   = id & 511;
        int lane = e >> 3, j = e & 7;
        int lrow = lane & 15, quad = lane >> 4;
        int h = blk >> 3;
        int t = blk & 7;
        int n = h * 128 + t * 16 + lrow;
        Wm_p[id] = f32_to_bf16(Wm[(size_t)n * MM + quad * 8 + j]);
    }
}

// ---- fused RLSTM, operand-swapped MFMA: D[n][batch] = W-tile x X^T ----
// C/D layout: col(lane&15) = batch-within-tile, row(quad*4+r) = n-within-tile
// => per lane: 4 consecutive n at one batch row => float4 epilogue.
__global__ __launch_bounds__(256) void rlstm_main(
    const float* __restrict__ input, const float* __restrict__ media,
    const float* __restrict__ h_t,   const float* __restrict__ c_t,
    const unsigned short* __restrict__ Wi_p, const float* __restrict__ bi,
    const unsigned short* __restrict__ Wm_p, const float* __restrict__ bm,
    float* __restrict__ out)
{
    const int tid  = threadIdx.x;
    const int wave = tid >> 6;
    const int lane = tid & 63;
    const int lrow = lane & 15;
    const int quad = lane >> 4;

    const int m0   = blockIdx.x * 32 + (wave >> 1) * 16;  // 16 batch rows per wave
    const int half = wave & 1;
    const int n0   = half * 128;

    const unsigned short* wip = Wi_p + (size_t)half * (NKC * 8 * 512);
    const unsigned short* wmp = Wm_p + (size_t)half * (8 * 512);

    const int arow = m0 + lrow;

    // prefetch media B-fragment early (needed only in epilogue)
    f32x4 md0 = *(const f32x4*)(media + (size_t)arow * MM + quad * 8);
    f32x4 md1 = *(const f32x4*)(media + (size_t)arow * MM + quad * 8 + 4);

    f32x4 accg[8];
#pragma unroll
    for (int t = 0; t < 8; ++t) accg[t] = (f32x4){0.f, 0.f, 0.f, 0.f};

    // ---- main GEMM: k in [0,128) from input, [128,384) from h_t ----
#pragma unroll
    for (int kc = 0; kc < NKC; ++kc) {
        const float* src = (kc < 4)
            ? (input + (size_t)arow * INW + kc * 32 + quad * 8)
            : (h_t   + (size_t)arow * HH  + (kc - 4) * 32 + quad * 8);
        f32x4 a0 = ((const f32x4*)src)[0];
        f32x4 a1 = ((const f32x4*)src)[1];
        bf16x8 xf = cvt8(a0, a1);
        const unsigned short* wb = wip + (size_t)kc * (8 * 512) + lane * 8;
#pragma unroll
        for (int t = 0; t < 8; ++t) {
            bf16x8 wf = *(const bf16x8*)(wb + t * 512);
            accg[t] = __builtin_amdgcn_mfma_f32_16x16x32_bf16(wf, xf, accg[t], 0, 0, 0);
        }
    }

    // ---- epilogue: media MFMA computed lazily per tile (1 acc live) ----
    bf16x8 mf = cvt8(md0, md1);
    const size_t outH = (size_t)BB * HH;
    const size_t rowbase = (size_t)arow * HH;
#pragma unroll
    for (int t = 0; t < 8; ++t) {
        bf16x8 wmf = *(const bf16x8*)(wmp + t * 512 + lane * 8);
        f32x4 am = __builtin_amdgcn_mfma_f32_16x16x32_bf16(
            wmf, mf, (f32x4){0.f, 0.f, 0.f, 0.f}, 0, 0, 0);

        const int nb = n0 + t * 16 + quad * 4;
        f32x4 bi4 = *(const f32x4*)(bi + nb);
        f32x4 bm4 = *(const f32x4*)(bm + nb);
        const size_t idx = rowbase + nb;
        f32x4 ct4 = *(const f32x4*)(c_t + idx);

        f32x4 h4, c4;
#pragma unroll
        for (int r = 0; r < 4; ++r) {
            float g    = accg[t][r] + bi4[r];
            float mp   = am[r] + bm4[r];
            float gate = sigmoid_f(g);
            float tg   = tanh_f(g);
            float c    = ct4[r] * gate + tg * gate;
            float cr   = tanh_f(c);
            float mg   = sigmoid_f(mp);
            float cf   = c - cr + cr * mg;
            float h    = tanh_f(cf) * gate;
            h4[r] = h; c4[r] = c;
        }
        *(f32x4*)(out + idx)            = h4;
        *(f32x4*)(out + idx + outH)     = h4;
        *(f32x4*)(out + idx + 2 * outH) = c4;
    }
}

extern "C" void kernel_launch(void* const* d_in, const int* in_sizes, int n_in,
                              void* d_out, int out_size, void* d_ws, size_t ws_size,
                              hipStream_t stream) {
    const float* input = (const float*)d_in[0];
    const float* media = (const float*)d_in[1];
    const float* h_t   = (const float*)d_in[2];
    const float* c_t   = (const float*)d_in[3];
    const float* Wi    = (const float*)d_in[4];
    const float* bi    = (const float*)d_in[5];
    const float* Wm    = (const float*)d_in[6];
    const float* bm    = (const float*)d_in[7];
    float* out = (float*)d_out;

    unsigned short* Wi_p = (unsigned short*)d_ws;
    unsigned short* Wm_p = Wi_p + 2 * NKC * 8 * 512;

    hipLaunchKernelGGL(pack_weights, dim3((2 * NKC * 8 * 512 + 255) / 256), dim3(256), 0, stream,
                       Wi, Wm, Wi_p, Wm_p);
    hipLaunchKernelGGL(rlstm_main, dim3(BB / 32), dim3(256), 0, stream,
                       input, media, h_t, c_t, Wi_p, bi, Wm_p, bm, out);
}